// Round 7
// baseline (4817.830 us; speedup 1.0000x reference)
//
#include <hip/hip_runtime.h>

typedef unsigned short u16;
typedef unsigned int   u32;
typedef unsigned long long u64;
typedef signed char    i8;
typedef __attribute__((ext_vector_type(4))) int  i32x4;
typedef __attribute__((ext_vector_type(2))) long i64x2;

// ---------------- problem constants ----------------
#define NSTEP 512

// ---------------- workspace layout (bytes) ----------------
#define OFF_QX8   0ull
#define SZ_QX8    (32768ull*512)            // x quantized, int8
#define OFF_QWT8  (OFF_QX8 + SZ_QX8)
#define SZ_QT8    (1536ull*512)             // W^T / R^T quantized, int8
#define OFF_QRT8  (OFF_QWT8 + SZ_QT8)
#define OFF_QWX2  (OFF_QRT8 + SZ_QT8)
#define SZ_QWX2   (512ull*4*512*4*3*4)      // Wx gate-packed dwords
#define OFF_QBX   (OFF_QWX2 + SZ_QWX2)      // 1536 int
#define OFF_QBR   (OFF_QBX + 6144)          // 1536 int
#define OFF_LUT   (OFF_QBR + 6144)          // 256 int sigmoid + 256 int tanh
#define OFF_RING  (OFF_LUT + 2048)          // 2 slots x 4 bg x 4096 u32 tagged words
#define RING_WORDS (2*4*4096)
#define SZ_RING   (RING_WORDS*4ull)
#define WS_NEED   (OFF_RING + SZ_RING)

// ---------------- helpers ----------------
__device__ __forceinline__ int iclip8(int v){ return v < -128 ? -128 : (v > 127 ? 127 : v); }

// round-half-even of (v / 2^k) for integer v (matches jnp.round on exact values)
__device__ __forceinline__ int rhe(int v, int k){
  int b = v >> k;
  int r = v & ((1 << k) - 1);
  int half = 1 << (k - 1);
  return b + ((r > half) || (r == half && (b & 1)));
}

__device__ __forceinline__ int qi8(float x, float s){
  float q = rintf(x * s);
  q = fminf(fmaxf(q, -128.f), 127.f);
  return (int)q;
}

// MFMA i8 wrapper: tolerate either i32x4- or i64x2-typed builtin signature.
template<typename V>
__device__ __forceinline__ auto mfma_i8_try(V a, V b, i32x4 c, int)
  -> decltype(__builtin_amdgcn_mfma_i32_16x16x64_i8(a, b, c, 0, 0, 0)) {
  return __builtin_amdgcn_mfma_i32_16x16x64_i8(a, b, c, 0, 0, 0);
}
template<typename V>
__device__ __forceinline__ i32x4 mfma_i8_try(V a, V b, i32x4 c, long) {
  return __builtin_amdgcn_mfma_i32_16x16x64_i8(
      __builtin_bit_cast(i64x2, a), __builtin_bit_cast(i64x2, b), c, 0, 0, 0);
}
__device__ __forceinline__ i32x4 mfma_i8(i32x4 a, i32x4 b, i32x4 c){
  return mfma_i8_try(a, b, c, 0);
}

// LLC-coherent (bypass L1+L2) store/zero — the PROVEN exchange fabric
__device__ __forceinline__ void st_llc(u32* p, u32 v){
  asm volatile("global_store_dword %0, %1, off sc0 sc1" :: "v"((u64)p), "v"(v) : "memory");
}
__device__ __forceinline__ void llc_zero16(u32* p){
  i32x4 z = {0,0,0,0};
  asm volatile("global_store_dwordx4 %0, %1, off sc0 sc1" :: "v"((u64)p), "v"(z) : "memory");
}

// ---------------- phase 0: quantization / tables ----------------
__global__ void k0a_qx(const float* __restrict__ x, u32* __restrict__ qx8, int n4){
  int i = blockIdx.x * blockDim.x + threadIdx.x;
  int st = gridDim.x * blockDim.x;
  for (; i < n4; i += st) {
    float4 v = ((const float4*)x)[i];
    u32 b0 = (u32)(qi8(v.x, 16.f) & 0xFF);
    u32 b1 = (u32)(qi8(v.y, 16.f) & 0xFF);
    u32 b2 = (u32)(qi8(v.z, 16.f) & 0xFF);
    u32 b3 = (u32)(qi8(v.w, 16.f) & 0xFF);
    qx8[i] = b0 | (b1 << 8) | (b2 << 16) | (b3 << 24);
  }
}

__global__ void k0b_qwr(const float* __restrict__ W, const float* __restrict__ Rm,
                        i8* __restrict__ qwT8, i8* __restrict__ qrT8){
  int idx = blockIdx.x * 256 + threadIdx.x;       // 0 .. 2*786432-1
  if (idx >= 2*786432) return;
  int m = idx >= 786432;
  int rem = idx - m * 786432;                     // = k*1536 + n (coalesced read)
  int k = rem / 1536;
  int n = rem - k * 1536;
  const float* s = m ? Rm : W;
  i8* d = m ? qrT8 : qwT8;
  d[n*512 + k] = (i8)qi8(s[rem], 1024.f);
}

__global__ void k0c_misc(const float* __restrict__ bx, const float* __restrict__ br,
                         int* __restrict__ qbx, int* __restrict__ qbr,
                         int* __restrict__ lut, u32* __restrict__ ring){
  int i = blockIdx.x * 256 + threadIdx.x;         // 4096 threads
  if (i < 1536) {
    qbx[i] = iclip8((int)rintf(bx[i] * 256.f));
    qbr[i] = iclip8((int)rintf(br[i] * 256.f));
  }
  if (i < 256) {
    double v = (i - 128) * 0.125;                 // all possible pre-activations
    float sg = (float)(1.0 / (1.0 + exp(-v)));
    int qs = (int)rintf(sg * 256.f);
    lut[i] = qs < 0 ? 0 : (qs > 255 ? 255 : qs);
    float th = (float)tanh(v);
    lut[256 + i] = iclip8((int)rintf(th * 128.f));
  }
  // zero the ring EVERY launch via LLC stores: tags >=1, so no leftover matches
  llc_zero16(ring + i*8);
  llc_zero16(ring + i*8 + 4);
}

// ---------------- phase 1: Wx = fq(xq @ Wq, 4), gate-packed dwords ----------
// (verbatim from R6, absmax=0 proven) element at (((t*4+bgrp)*512+hcol)*4+g)*3+gate,
// dword packs batch rows bgrp*16 + 4g + 0..3.
__global__ __launch_bounds__(256) void k1_gemm_wx(const i8* __restrict__ qx8,
                                                  const i8* __restrict__ qwT8,
                                                  u32* __restrict__ qwx2){
  __shared__ i8 xs[128][80];
  __shared__ i8 ws[128][80];
  int bid = blockIdx.x;
  int n0 = (bid % 12) * 128;
  int m0 = (bid / 12) * 128;
  int tid = threadIdx.x;
  int lane = tid & 63, wid = tid >> 6;
  int wm = wid >> 1, wn = wid & 1;
  int g = lane >> 4, l15 = lane & 15;

  i32x4 acc[4][4] = {};
  for (int kc = 0; kc < 512; kc += 64) {
    __syncthreads();
#pragma unroll
    for (int p = 0; p < 4; p++) {
      int idx = p*256 + tid;
      int mat = idx >> 9;
      int i2  = idx & 511;
      int r   = i2 >> 2;
      int c16 = (i2 & 3) << 4;
      const i8* src = mat ? qwT8 : qx8;
      int base = mat ? n0 : m0;
      uint4 val = *(const uint4*)&src[(size_t)(base + r)*512 + kc + c16];
      if (mat) *(uint4*)&ws[r][c16] = val;
      else     *(uint4*)&xs[r][c16] = val;
    }
    __syncthreads();
    i32x4 a[4], b[4];
#pragma unroll
    for (int t = 0; t < 4; t++) {
      a[t] = *(const i32x4*)&xs[wm*64 + t*16 + l15][g*16];
      b[t] = *(const i32x4*)&ws[wn*64 + t*16 + l15][g*16];
    }
#pragma unroll
    for (int i = 0; i < 4; i++)
#pragma unroll
      for (int j = 0; j < 4; j++)
        acc[i][j] = mfma_i8(a[i], b[j], acc[i][j]);
  }
  const int t4idx = (bid / 12) * 2 + wm;
#pragma unroll
  for (int i = 0; i < 4; i++)
#pragma unroll
    for (int j = 0; j < 4; j++) {
      u32 d = 0;
#pragma unroll
      for (int r = 0; r < 4; r++)
        d |= (u32)(iclip8(rhe(acc[i][j][r], 10)) & 0xFF) << (8*r);
      int col1536 = n0 + wn*64 + j*16 + l15;
      int gate = col1536 >> 9;
      int hcol = col1536 & 511;
      qwx2[((((size_t)t4idx*4 + i)*512 + hcol)*4 + g)*3 + gate] = d;
    }
}

// ---------------- phase 2: 512-step recurrence, 16 big agents ----------------
// 16 WGs x 1024 threads: (bg = bid&3, wq = bid>>2) owns 128 h-cols. 16 waves =
// 8 col-groups (cgl, 16 cols) x 2 K-halves (ks, K=256). Wave polls only its
// K-half (128B, exactly 2 producer WGs). K-halves meet via parity LDS partials
// + ONE barrier/step; ks=0 finishes in-lane (gates z/r/n share the lane) and
// publishes. LLC tagged-word ring fabric, verbatim from proven rounds.
__global__ __launch_bounds__(1024, 1) void k2_gru(const float* __restrict__ h0,
                                                  const u32* __restrict__ qwx2,
                                                  const i8*  __restrict__ qrT8,
                                                  const int* __restrict__ qbx,
                                                  const int* __restrict__ qbr,
                                                  const int* __restrict__ lut,
                                                  u32* __restrict__ ring,
                                                  float* __restrict__ out){
  const int bid = blockIdx.x;
  const int bg  = bid & 3;
  const int wq  = bid >> 2;                       // 0..3: col block of 128
  const int tid = threadIdx.x;
  const int lane = tid & 63, wid = tid >> 6;      // 16 waves
  const int g = lane >> 4, l15 = lane & 15;
  const int cgl = wid & 7;                        // 16-col group within block
  const int ks  = wid >> 3;                       // K-half: 0 -> [0,256), 1 -> [256,512)

  __shared__ int l_sig[256], l_th[256];
  __shared__ int red[2*8*3*272];                  // [par][cgl][gate][(4g+r)*17+l15]

  if (tid < 256) { l_sig[tid] = lut[tid]; l_th[tid] = lut[256 + tid]; }
  __syncthreads();

  const int col = wq*128 + cgl*16 + l15;          // lane's h-column

  // ---- R fragments: 3 gate-tiles x 4 k-chunks of this K-half (48 VGPR)
  i32x4 rf[3][4];
#pragma unroll
  for (int gate = 0; gate < 3; gate++) {
    const i8* rp = qrT8 + (size_t)(gate*512 + col)*512 + ks*256 + g*16;
#pragma unroll
    for (int m = 0; m < 4; m++)
      rf[gate][m] = *(const i32x4*)(rp + m*64);
  }

  const int bxz = qbx[col], bxr = qbx[512 + col], bxn = qbx[1024 + col];
  const int brz = qbr[col], brr = qbr[512 + col], brn = qbr[1024 + col];

  // ---- h state (ks=0 only): rows 4g+r of batch group bg, this lane's col
  int qh[4] = {0, 0, 0, 0};
  if (ks == 0) {
#pragma unroll
    for (int r = 0; r < 4; r++)
      qh[r] = qi8(h0[(size_t)(bg*16 + g*4 + r)*512 + col], 128.f);
  }

  const u64 ringb = (u64)ring;
  // publish geometry (R6-verbatim): word packs cols (kp,kp+1) of one row
  const int even = ((lane & 1) == 0);
  const int kp = col & ~1;
  const int rA = g*4 + (even ? 0 : 2);
  const int pw = ((((kp >> 7)*4 + ((kp >> 4) & 3))*16 + rA)*16)
               + (((kp >> 6) & 1) << 3) + ((kp >> 1) & 7);
  const int sh = even ? 0 : 16;

  // ---- publish h(0): slot 0, tag 1 (ks=0 lanes cover all of this WG's cols)
  if (ks == 0) {
    u32 my = (u32)(qh[0] & 0xFF) | ((u32)(qh[1] & 0xFF) << 8)
           | ((u32)(qh[2] & 0xFF) << 16) | ((u32)qh[3] << 24);
    u32 nb = (u32)__shfl_xor((int)my, 1, 64);
    u32 lo = even ? my : nb, hi = even ? nb : my;
    u32 wA = ((lo >> sh) & 0xFF) | (((hi >> sh) & 0xFF) << 8) | (1u << 16);
    u32 wB = ((lo >> (sh + 8)) & 0xFF) | (((hi >> (sh + 8)) & 0xFF) << 8) | (1u << 16);
    u64 a = ringb + (u64)(bg*16384 + pw*4);
    st_llc((u32*)a, wA);
    st_llc((u32*)(a + 64), wB);
  }

  // ---- Wx preload t=0 (ks=0 only)
  u32 wzd = 0, wrd = 0, wgd = 0;
  if (ks == 0) {
    const u32* p = qwx2 + (((size_t)bg*512 + col)*4 + g)*3;
    wzd = p[0]; wrd = p[1]; wgd = p[2];
  }

  // poll regions: K-half ks = image regions w=2ks, 2ks+1 (64B/lane each)
  const u64 laneA = (u64)(((2*ks    )*64 + lane) * 64);
  const u64 laneB = (u64)(((2*ks + 1)*64 + lane) * 64);

  for (int t = 0; t < NSTEP; t++) {
    const u32 want2 = (u32)(t + 1) | ((u32)(t + 1) << 16);
    const u64 sb = ringb + (u64)(((t & 1)*4 + bg) * 16384);
    const u64 a0 = sb + laneA, a1 = sb + laneB;
    uint4 p0, p1, p2, p3, p4, p5, p6, p7;
    int rounds = 0;
    for (;;) {
      asm volatile(
        "global_load_dwordx4 %0, %8, off sc0 sc1\n\t"
        "global_load_dwordx4 %1, %8, off offset:16 sc0 sc1\n\t"
        "global_load_dwordx4 %2, %8, off offset:32 sc0 sc1\n\t"
        "global_load_dwordx4 %3, %8, off offset:48 sc0 sc1\n\t"
        "global_load_dwordx4 %4, %9, off sc0 sc1\n\t"
        "global_load_dwordx4 %5, %9, off offset:16 sc0 sc1\n\t"
        "global_load_dwordx4 %6, %9, off offset:32 sc0 sc1\n\t"
        "global_load_dwordx4 %7, %9, off offset:48 sc0 sc1\n\t"
        "s_waitcnt vmcnt(0)"
        : "=&v"(p0), "=&v"(p1), "=&v"(p2), "=&v"(p3),
          "=&v"(p4), "=&v"(p5), "=&v"(p6), "=&v"(p7)
        : "v"(a0), "v"(a1)
        : "memory");
      u32 diff = 0u;
#define TCHK(P) \
      diff |= __builtin_amdgcn_perm((P).y, (P).x, 0x07060302u) ^ want2; \
      diff |= __builtin_amdgcn_perm((P).w, (P).z, 0x07060302u) ^ want2;
      TCHK(p0) TCHK(p1) TCHK(p2) TCHK(p3) TCHK(p4) TCHK(p5) TCHK(p6) TCHK(p7)
#undef TCHK
      if (diff == 0u) break;
      if (++rounds > (1 << 22)) break;            // hang-prevention only
      if (rounds >= 2) __builtin_amdgcn_s_sleep(1);
    }

    // next-step Wx prefetch (ks=0; hides under MFMAs/barrier)
    u32 nz = 0, nr = 0, ng = 0;
    if (ks == 0 && t < NSTEP - 1) {
      const u32* p = qwx2 + ((((size_t)(t + 1)*4 + bg)*512 + col)*4 + g)*3;
      nz = p[0]; nr = p[1]; ng = p[2];
    }

    // ---- pack A (strip tags) and run 12 MFMAs over this K-half
    i32x4 acc0 = {}, acc1 = {}, acc2 = {};
    {
      i32x4 A0, A1, A2, A3;
#define PACKA(A, Pa, Pb) \
      A.x = (int)__builtin_amdgcn_perm((Pa).y, (Pa).x, 0x05040100u); \
      A.y = (int)__builtin_amdgcn_perm((Pa).w, (Pa).z, 0x05040100u); \
      A.z = (int)__builtin_amdgcn_perm((Pb).y, (Pb).x, 0x05040100u); \
      A.w = (int)__builtin_amdgcn_perm((Pb).w, (Pb).z, 0x05040100u);
      PACKA(A0, p0, p1) PACKA(A1, p2, p3) PACKA(A2, p4, p5) PACKA(A3, p6, p7)
#undef PACKA
      acc0 = mfma_i8(A0, rf[0][0], acc0); acc1 = mfma_i8(A0, rf[1][0], acc1);
      acc2 = mfma_i8(A0, rf[2][0], acc2);
      acc0 = mfma_i8(A1, rf[0][1], acc0); acc1 = mfma_i8(A1, rf[1][1], acc1);
      acc2 = mfma_i8(A1, rf[2][1], acc2);
      acc0 = mfma_i8(A2, rf[0][2], acc0); acc1 = mfma_i8(A2, rf[1][2], acc1);
      acc2 = mfma_i8(A2, rf[2][2], acc2);
      acc0 = mfma_i8(A3, rf[0][3], acc0); acc1 = mfma_i8(A3, rf[1][3], acc1);
      acc2 = mfma_i8(A3, rf[2][3], acc2);
    }

    // ---- ks=1: hand partials to ks=0 through parity LDS
    const int par = t & 1;
    int* rb = &red[(par*8 + cgl)*3*272];
    if (ks == 1) {
#pragma unroll
      for (int r = 0; r < 4; r++) {
        rb[0*272 + (g*4 + r)*17 + l15] = acc0[r];
        rb[1*272 + (g*4 + r)*17 + l15] = acc1[r];
        rb[2*272 + (g*4 + r)*17 + l15] = acc2[r];
      }
    }
    __syncthreads();                              // the ONLY barrier per step

    if (ks == 0) {
      // ---- finish sums + gates in-lane, update h, publish, store out
      u32 my;
      {
        u32 acc_my = 0;
#pragma unroll
        for (int r = 0; r < 4; r++) {
          int S0 = acc0[r] + rb[0*272 + (g*4 + r)*17 + l15];
          int S1 = acc1[r] + rb[1*272 + (g*4 + r)*17 + l15];
          int S2 = acc2[r] + rb[2*272 + (g*4 + r)*17 + l15];
          int rz = iclip8(rhe(iclip8(rhe(S0, 13))*16 + brz, 4));
          int rr = iclip8(rhe(iclip8(rhe(S1, 13))*16 + brr, 4));
          int rg = iclip8(rhe(iclip8(rhe(S2, 13))*16 + brn, 4));
          int wz = (int)(i8)((wzd >> (8*r)) & 0xFF);
          int wr = (int)(i8)((wrd >> (8*r)) & 0xFF);
          int wg = (int)(i8)((wgd >> (8*r)) & 0xFF);
          int uz  = l_sig[128 + iclip8(rhe(16*(wz + rz) + bxz, 5))];
          int ur  = l_sig[128 + iclip8(rhe(16*(wr + rr) + bxr, 5))];
          int qrh = iclip8(rhe(ur * rg, 8));
          int qg  = l_th[128 + iclip8(rhe(16*(wg + qrh) + bxn, 5))];
          int qold = iclip8(rhe(uz * qh[r], 8));
          int qnew = iclip8(rhe((256 - uz) * qg, 8));
          qh[r] = iclip8(qold + qnew);
          acc_my |= (u32)(qh[r] & 0xFF) << (8*r);
        }
        my = acc_my;
      }
      // publish h(t+1) FIRST (earliest cross-WG visibility)
      {
        u32 nb = (u32)__shfl_xor((int)my, 1, 64);
        u32 lo = even ? my : nb, hi = even ? nb : my;
        u32 tg = (u32)(t + 2) << 16;
        u32 wA = ((lo >> sh) & 0xFF) | (((hi >> sh) & 0xFF) << 8) | tg;
        u32 wB = ((lo >> (sh + 8)) & 0xFF) | (((hi >> (sh + 8)) & 0xFF) << 8) | tg;
        u64 a = ringb + (u64)((((t + 1) & 1)*4 + bg)*16384 + pw*4);
        st_llc((u32*)a, wA);
        st_llc((u32*)(a + 64), wB);
      }
#pragma unroll
      for (int r = 0; r < 4; r++)
        out[((size_t)t*64 + bg*16 + g*4 + r)*512 + col] = qh[r] * 0.0078125f;

      wzd = nz; wrd = nr; wgd = ng;
    }
  }
}

// ---------------- launch ----------------
extern "C" void kernel_launch(void* const* d_in, const int* in_sizes, int n_in,
                              void* d_out, int out_size, void* d_ws, size_t ws_size,
                              hipStream_t stream) {
  const float* x  = (const float*)d_in[0];
  const float* h0 = (const float*)d_in[1];
  const float* W  = (const float*)d_in[2];
  const float* R  = (const float*)d_in[3];
  const float* bx = (const float*)d_in[4];
  const float* br = (const float*)d_in[5];
  float* out = (float*)d_out;

  if (ws_size < WS_NEED) return;   // insufficient scratch; fail loudly

  char* ws = (char*)d_ws;
  i8*  qx8   = (i8*) (ws + OFF_QX8);
  i8*  qwT8  = (i8*) (ws + OFF_QWT8);
  i8*  qrT8  = (i8*) (ws + OFF_QRT8);
  u32* qwx2  = (u32*)(ws + OFF_QWX2);
  int* qbx   = (int*)(ws + OFF_QBX);
  int* qbr   = (int*)(ws + OFF_QBR);
  int* lut   = (int*)(ws + OFF_LUT);
  u32* ring  = (u32*)(ws + OFF_RING);

  k0a_qx  <<<2048, 256, 0, stream>>>(x, (u32*)qx8, 32768*512/4);
  k0b_qwr <<<6144, 256, 0, stream>>>(W, R, qwT8, qrT8);
  k0c_misc<<<16,   256, 0, stream>>>(bx, br, qbx, qbr, lut, ring);
  k1_gemm_wx<<<3072, 256, 0, stream>>>(qx8, qwT8, qwx2);
  k2_gru  <<<16, 1024, 0, stream>>>(h0, qwx2, qrT8, qbx, qbr, lut, ring, out);
}

// Round 8
// 1599.888 us; speedup vs baseline: 3.0114x; 3.0114x over previous
//
#include <hip/hip_runtime.h>

typedef unsigned short u16;
typedef unsigned int   u32;
typedef unsigned long long u64;
typedef signed char    i8;
typedef __attribute__((ext_vector_type(4))) int  i32x4;
typedef __attribute__((ext_vector_type(2))) long i64x2;

// ---------------- problem constants ----------------
#define NSTEP 512

// ---------------- workspace layout (bytes) ----------------
#define OFF_QX8   0ull
#define SZ_QX8    (32768ull*512)            // x quantized, int8
#define OFF_QWT8  (OFF_QX8 + SZ_QX8)
#define SZ_QT8    (1536ull*512)             // W^T / R^T quantized, int8
#define OFF_QRT8  (OFF_QWT8 + SZ_QT8)
#define OFF_QWX   (OFF_QRT8 + SZ_QT8)
#define SZ_QWX    (32768ull*1536)           // Wx quantized, int8 row-major
#define OFF_QBX   (OFF_QWX + SZ_QWX)        // 1536 int
#define OFF_QBR   (OFF_QBX + 6144)          // 1536 int
#define OFF_LUT   (OFF_QBR + 6144)          // 256 int sigmoid + 256 int tanh
#define OFF_RING  (OFF_LUT + 2048)          // 2 slots x 4 bg x 4096 u32 tagged words
#define RING_WORDS (2*4*4096)
#define SZ_RING   (RING_WORDS*4ull)
#define WS_NEED   (OFF_RING + SZ_RING)

// ---------------- helpers ----------------
__device__ __forceinline__ int iclip8(int v){ return v < -128 ? -128 : (v > 127 ? 127 : v); }

// round-half-even of (v / 2^k) for integer v (matches jnp.round on exact values)
__device__ __forceinline__ int rhe(int v, int k){
  int b = v >> k;
  int r = v & ((1 << k) - 1);
  int half = 1 << (k - 1);
  return b + ((r > half) || (r == half && (b & 1)));
}

__device__ __forceinline__ int qi8(float x, float s){
  float q = rintf(x * s);
  q = fminf(fmaxf(q, -128.f), 127.f);
  return (int)q;
}

// MFMA i8 wrapper: tolerate either i32x4- or i64x2-typed builtin signature.
template<typename V>
__device__ __forceinline__ auto mfma_i8_try(V a, V b, i32x4 c, int)
  -> decltype(__builtin_amdgcn_mfma_i32_16x16x64_i8(a, b, c, 0, 0, 0)) {
  return __builtin_amdgcn_mfma_i32_16x16x64_i8(a, b, c, 0, 0, 0);
}
template<typename V>
__device__ __forceinline__ i32x4 mfma_i8_try(V a, V b, i32x4 c, long) {
  return __builtin_amdgcn_mfma_i32_16x16x64_i8(
      __builtin_bit_cast(i64x2, a), __builtin_bit_cast(i64x2, b), c, 0, 0, 0);
}
__device__ __forceinline__ i32x4 mfma_i8(i32x4 a, i32x4 b, i32x4 c){
  return mfma_i8_try(a, b, c, 0);
}

// LLC-coherent (bypass L1+L2) store/zero — the PROVEN exchange fabric
__device__ __forceinline__ void st_llc(u32* p, u32 v){
  asm volatile("global_store_dword %0, %1, off sc0 sc1" :: "v"((u64)p), "v"(v) : "memory");
}
__device__ __forceinline__ void llc_zero16(u32* p){
  i32x4 z = {0,0,0,0};
  asm volatile("global_store_dwordx4 %0, %1, off sc0 sc1" :: "v"((u64)p), "v"(z) : "memory");
}

// ---------------- phase 0: quantization / tables ----------------
__global__ void k0a_qx(const float* __restrict__ x, u32* __restrict__ qx8, int n4){
  int i = blockIdx.x * blockDim.x + threadIdx.x;
  int st = gridDim.x * blockDim.x;
  for (; i < n4; i += st) {
    float4 v = ((const float4*)x)[i];
    u32 b0 = (u32)(qi8(v.x, 16.f) & 0xFF);
    u32 b1 = (u32)(qi8(v.y, 16.f) & 0xFF);
    u32 b2 = (u32)(qi8(v.z, 16.f) & 0xFF);
    u32 b3 = (u32)(qi8(v.w, 16.f) & 0xFF);
    qx8[i] = b0 | (b1 << 8) | (b2 << 16) | (b3 << 24);
  }
}

__global__ void k0b_qwr(const float* __restrict__ W, const float* __restrict__ Rm,
                        i8* __restrict__ qwT8, i8* __restrict__ qrT8){
  int idx = blockIdx.x * 256 + threadIdx.x;       // 0 .. 2*786432-1
  if (idx >= 2*786432) return;
  int m = idx >= 786432;
  int rem = idx - m * 786432;                     // = k*1536 + n (coalesced read)
  int k = rem / 1536;
  int n = rem - k * 1536;
  const float* s = m ? Rm : W;
  i8* d = m ? qrT8 : qwT8;
  d[n*512 + k] = (i8)qi8(s[rem], 1024.f);
}

__global__ void k0c_misc(const float* __restrict__ bx, const float* __restrict__ br,
                         int* __restrict__ qbx, int* __restrict__ qbr,
                         int* __restrict__ lut, u32* __restrict__ ring){
  int i = blockIdx.x * 256 + threadIdx.x;         // 4096 threads
  if (i < 1536) {
    qbx[i] = iclip8((int)rintf(bx[i] * 256.f));
    qbr[i] = iclip8((int)rintf(br[i] * 256.f));
  }
  if (i < 256) {
    double v = (i - 128) * 0.125;                 // all possible pre-activations
    float sg = (float)(1.0 / (1.0 + exp(-v)));
    int qs = (int)rintf(sg * 256.f);
    lut[i] = qs < 0 ? 0 : (qs > 255 ? 255 : qs);
    float th = (float)tanh(v);
    lut[256 + i] = iclip8((int)rintf(th * 128.f));
  }
  // zero the ring EVERY launch via LLC stores: tags >=1, so no leftover matches
  llc_zero16(ring + i*8);
  llc_zero16(ring + i*8 + 4);
}

// ---------------- phase 1: Wx = fq(xq @ Wq, 4), stored int8 row-major -------
// (R5-verbatim, absmax=0 proven) 128x128 tile, BK=64, int8 MFMA.
__global__ __launch_bounds__(256) void k1_gemm_wx(const i8* __restrict__ qx8,
                                                  const i8* __restrict__ qwT8,
                                                  i8* __restrict__ qwx){
  __shared__ i8 xs[128][80];
  __shared__ i8 ws[128][80];
  int bid = blockIdx.x;
  int n0 = (bid % 12) * 128;
  int m0 = (bid / 12) * 128;
  int tid = threadIdx.x;
  int lane = tid & 63, wid = tid >> 6;
  int wm = wid >> 1, wn = wid & 1;
  int g = lane >> 4, l15 = lane & 15;

  i32x4 acc[4][4] = {};
  for (int kc = 0; kc < 512; kc += 64) {
    __syncthreads();
#pragma unroll
    for (int p = 0; p < 4; p++) {
      int idx = p*256 + tid;
      int mat = idx >> 9;
      int i2  = idx & 511;
      int r   = i2 >> 2;
      int c16 = (i2 & 3) << 4;
      const i8* src = mat ? qwT8 : qx8;
      int base = mat ? n0 : m0;
      uint4 val = *(const uint4*)&src[(size_t)(base + r)*512 + kc + c16];
      if (mat) *(uint4*)&ws[r][c16] = val;
      else     *(uint4*)&xs[r][c16] = val;
    }
    __syncthreads();
    i32x4 a[4], b[4];
#pragma unroll
    for (int t = 0; t < 4; t++) {
      a[t] = *(const i32x4*)&xs[wm*64 + t*16 + l15][g*16];
      b[t] = *(const i32x4*)&ws[wn*64 + t*16 + l15][g*16];
    }
#pragma unroll
    for (int i = 0; i < 4; i++)
#pragma unroll
      for (int j = 0; j < 4; j++)
        acc[i][j] = mfma_i8(a[i], b[j], acc[i][j]);
  }
#pragma unroll
  for (int i = 0; i < 4; i++)
#pragma unroll
    for (int j = 0; j < 4; j++)
#pragma unroll
      for (int r = 0; r < 4; r++) {
        int q = iclip8(rhe(acc[i][j][r], 10));
        int row = m0 + wm*64 + i*16 + g*4 + r;
        int col = n0 + wn*64 + j*16 + l15;
        qwx[(size_t)row * 1536 + col] = (i8)q;
      }
}

// ---------------- phase 2: 512-step recurrence (R2 topology, best body) -----
// 64 WGs: bg owns 16 batch rows, cg owns 32 h-cols; wave = K-slice of 128
// (per-LANE poll = 64B from exactly ONE producer WG). h exchanged via the
// proven LLC tagged-word ring, fence-free. Body: 12 i8 MFMAs + perm-pack,
// fused exact-i32 reduce+gates, ONE barrier/step, busy-poll.
__global__ __launch_bounds__(256, 1) void k2_gru(const float* __restrict__ h0,
                                                 const i8*  __restrict__ qwx,
                                                 const i8*  __restrict__ qrT8,
                                                 const int* __restrict__ qbx,
                                                 const int* __restrict__ qbr,
                                                 const int* __restrict__ lut,
                                                 u32* __restrict__ ring,
                                                 float* __restrict__ out){
  const int bid = blockIdx.x;
  const int bg  = (bid & 7) >> 1;                 // R2's XCD-spreading mapping
  const int cg  = ((bid >> 3) << 1) | (bid & 1);  // 0..15
  const int tid = threadIdx.x;
  const int lane = tid & 63, wid = tid >> 6;      // wave = K-slice of 128
  const int g = lane >> 4, l15 = lane & 15;

  __shared__ int l_sig[256], l_th[256];
  __shared__ int red[2][4][16][100];              // [parity][wave][row][96+pad]

  l_sig[tid] = lut[tid];
  l_th[tid]  = lut[256 + tid];

  // ---- R fragments (B operand), int8, resident: 6 n-tiles x 2 k-chunks
  i32x4 rf[6][2];
#pragma unroll
  for (int n = 0; n < 6; n++) {
    int colR = (n >> 1)*512 + cg*32 + (n & 1)*16 + l15;   // B: col = lane&15
#pragma unroll
    for (int m = 0; m < 2; m++)
      rf[n][m] = *(const i32x4*)&qrT8[(size_t)colR*512 + wid*128 + m*64 + g*16];
  }

  // ---- own h state: 2 elements per thread (row = tid>>4, cols c0,c0+1)
  const int row = tid >> 4;
  const int c0  = (tid & 15) << 1;
  int bxz[2], bxr[2], bxn[2], brz[2], brr[2], brn[2];
#pragma unroll
  for (int cc = 0; cc < 2; cc++) {
    int col = cg*32 + c0 + cc;
    bxz[cc] = qbx[col]; bxr[cc] = qbx[512 + col]; bxn[cc] = qbx[1024 + col];
    brz[cc] = qbr[col]; brr[cc] = qbr[512 + col]; brn[cc] = qbr[1024 + col];
  }
  int qh[2];
  {
    float2 h2 = *(const float2*)&h0[(size_t)(bg*16 + row)*512 + cg*32 + c0];
    qh[0] = qi8(h2.x, 128.f); qh[1] = qi8(h2.y, 128.f);
  }

  // producer word index (proven layout): k = cg*32+c0, word = 2 int8 + tag16
  const int kprod = cg*32 + c0;
  const int pwidx = ((((kprod >> 7)*4 + ((kprod >> 4) & 3))*16 + row)*16)
                  + (((kprod >> 6) & 1) << 3) + ((kprod >> 1) & 7);

  const u64 ringb = (u64)ring;

  // ---- publish h(0): slot 0, tag 1
  {
    u32 wv = (u32)(qh[0] & 0xFF) | ((u32)(qh[1] & 0xFF) << 8) | (1u << 16);
    st_llc((u32*)(ringb + (u64)(bg*16384 + pwidx*4)), wv);
  }

  // ---- Wx pre-load for t=0 (one step ahead thereafter)
  u32 wzw, wrw, wgw;
  {
    const i8* wxp = qwx + (size_t)(bg*16 + row)*1536 + cg*32;
    wzw = *(const u16*)(wxp + c0);
    wrw = *(const u16*)(wxp + 512 + c0);
    wgw = *(const u16*)(wxp + 1024 + c0);
  }

  // consumer poll base: lane reads 64B covering its 32 k-values (16 words)
  const u64 laneoff = (u64)((wid*64 + lane) * 64);

  for (int t = 0; t < NSTEP; t++) {
    const u32 want2 = (u32)(t + 1) | ((u32)(t + 1) << 16);
    const u64 aP = ringb + (u64)(((t & 1)*4 + bg) * 16384) + laneoff;
    uint4 P0, P1, P2, P3;
    int rounds = 0;
    for (;;) {
      asm volatile(
        "global_load_dwordx4 %0, %4, off sc0 sc1\n\t"
        "global_load_dwordx4 %1, %4, off offset:16 sc0 sc1\n\t"
        "global_load_dwordx4 %2, %4, off offset:32 sc0 sc1\n\t"
        "global_load_dwordx4 %3, %4, off offset:48 sc0 sc1\n\t"
        "s_waitcnt vmcnt(0)"
        : "=&v"(P0), "=&v"(P1), "=&v"(P2), "=&v"(P3) : "v"(aP) : "memory");
      u32 diff;
      diff  = __builtin_amdgcn_perm(P0.y, P0.x, 0x07060302u) ^ want2;
      diff |= __builtin_amdgcn_perm(P0.w, P0.z, 0x07060302u) ^ want2;
      diff |= __builtin_amdgcn_perm(P1.y, P1.x, 0x07060302u) ^ want2;
      diff |= __builtin_amdgcn_perm(P1.w, P1.z, 0x07060302u) ^ want2;
      diff |= __builtin_amdgcn_perm(P2.y, P2.x, 0x07060302u) ^ want2;
      diff |= __builtin_amdgcn_perm(P2.w, P2.z, 0x07060302u) ^ want2;
      diff |= __builtin_amdgcn_perm(P3.y, P3.x, 0x07060302u) ^ want2;
      diff |= __builtin_amdgcn_perm(P3.w, P3.z, 0x07060302u) ^ want2;
      if (diff == 0u) break;
      if (++rounds > (1 << 22)) break;            // hang-prevention only
      if (rounds > 16) __builtin_amdgcn_s_sleep(1);  // busy-poll first
    }

    // next-step Wx prefetch (latency hides under compute + next poll)
    u32 nzw = 0, nrw = 0, ngw = 0;
    if (t < NSTEP - 1) {
      const i8* wxp = qwx + (size_t)(t + 1)*98304 + (size_t)(bg*16 + row)*1536 + cg*32;
      nzw = *(const u16*)(wxp + c0);
      nrw = *(const u16*)(wxp + 512 + c0);
      ngw = *(const u16*)(wxp + 1024 + c0);
    }

    // ---- pack A (strip tags) and run the 12 MFMAs
    i32x4 acc[6] = {};
    {
      i32x4 a0, a1;
      a0.x = (int)__builtin_amdgcn_perm(P0.y, P0.x, 0x05040100u);
      a0.y = (int)__builtin_amdgcn_perm(P0.w, P0.z, 0x05040100u);
      a0.z = (int)__builtin_amdgcn_perm(P1.y, P1.x, 0x05040100u);
      a0.w = (int)__builtin_amdgcn_perm(P1.w, P1.z, 0x05040100u);
      a1.x = (int)__builtin_amdgcn_perm(P2.y, P2.x, 0x05040100u);
      a1.y = (int)__builtin_amdgcn_perm(P2.w, P2.z, 0x05040100u);
      a1.z = (int)__builtin_amdgcn_perm(P3.y, P3.x, 0x05040100u);
      a1.w = (int)__builtin_amdgcn_perm(P3.w, P3.z, 0x05040100u);
#pragma unroll
      for (int n = 0; n < 6; n++) acc[n] = mfma_i8(a0, rf[n][0], acc[n]);
#pragma unroll
      for (int n = 0; n < 6; n++) acc[n] = mfma_i8(a1, rf[n][1], acc[n]);
    }

    // ---- per-wave partials to LDS (parity buffer), ONE barrier per step
    const int par = t & 1;
#pragma unroll
    for (int n = 0; n < 6; n++)
#pragma unroll
      for (int r = 0; r < 4; r++)
        red[par][wid][g*4 + r][n*16 + l15] = acc[n][r];
    __syncthreads();

    // ---- fused reduce (int2 loads) + quantize + gates for 2 columns
    const int* rbase = &red[par][0][row][0];      // wave stride = 1600 ints
    int rz[2], rr[2], rg[2];
    {
      int2 Sz = {0,0}, Sr = {0,0}, Sn = {0,0};
#pragma unroll
      for (int w = 0; w < 4; w++) {
        int2 vz = *(const int2*)&rbase[w*1600      + c0];
        int2 vr = *(const int2*)&rbase[w*1600 + 32 + c0];
        int2 vn = *(const int2*)&rbase[w*1600 + 64 + c0];
        Sz.x += vz.x; Sz.y += vz.y;
        Sr.x += vr.x; Sr.y += vr.y;
        Sn.x += vn.x; Sn.y += vn.y;
      }
      rz[0] = iclip8(rhe(iclip8(rhe(Sz.x, 13))*16 + brz[0], 4));
      rz[1] = iclip8(rhe(iclip8(rhe(Sz.y, 13))*16 + brz[1], 4));
      rr[0] = iclip8(rhe(iclip8(rhe(Sr.x, 13))*16 + brr[0], 4));
      rr[1] = iclip8(rhe(iclip8(rhe(Sr.y, 13))*16 + brr[1], 4));
      rg[0] = iclip8(rhe(iclip8(rhe(Sn.x, 13))*16 + brn[0], 4));
      rg[1] = iclip8(rhe(iclip8(rhe(Sn.y, 13))*16 + brn[1], 4));
    }
#pragma unroll
    for (int cc = 0; cc < 2; cc++) {
      int wz = (int)(i8)((wzw >> (8*cc)) & 0xFF);
      int wr = (int)(i8)((wrw >> (8*cc)) & 0xFF);
      int wg = (int)(i8)((wgw >> (8*cc)) & 0xFF);
      int uz  = l_sig[128 + iclip8(rhe(16*(wz + rz[cc]) + bxz[cc], 5))];
      int ur  = l_sig[128 + iclip8(rhe(16*(wr + rr[cc]) + bxr[cc], 5))];
      int qrh = iclip8(rhe(ur * rg[cc], 8));
      int qg  = l_th[128 + iclip8(rhe(16*(wg + qrh) + bxn[cc], 5))];
      int qold = iclip8(rhe(uz * qh[cc], 8));
      int qnew = iclip8(rhe((256 - uz) * qg, 8));
      qh[cc] = iclip8(qold + qnew);
    }

    // ---- publish h(t+1) FIRST (earliest cross-WG visibility), then out
    {
      u32 tg = (u32)(t + 2) << 16;
      u32 wv = (u32)(qh[0] & 0xFF) | ((u32)(qh[1] & 0xFF) << 8) | tg;
      st_llc((u32*)(ringb + (u64)((((t + 1) & 1)*4 + bg)*16384 + pwidx*4)), wv);
    }
    float2 ov;
    ov.x = qh[0] * 0.0078125f; ov.y = qh[1] * 0.0078125f;
    *(float2*)&out[((size_t)t*64 + bg*16 + row)*512 + cg*32 + c0] = ov;

    wzw = nzw; wrw = nrw; wgw = ngw;
  }
}

// ---------------- launch ----------------
extern "C" void kernel_launch(void* const* d_in, const int* in_sizes, int n_in,
                              void* d_out, int out_size, void* d_ws, size_t ws_size,
                              hipStream_t stream) {
  const float* x  = (const float*)d_in[0];
  const float* h0 = (const float*)d_in[1];
  const float* W  = (const float*)d_in[2];
  const float* R  = (const float*)d_in[3];
  const float* bx = (const float*)d_in[4];
  const float* br = (const float*)d_in[5];
  float* out = (float*)d_out;

  if (ws_size < WS_NEED) return;   // insufficient scratch; fail loudly

  char* ws = (char*)d_ws;
  i8*  qx8   = (i8*) (ws + OFF_QX8);
  i8*  qwT8  = (i8*) (ws + OFF_QWT8);
  i8*  qrT8  = (i8*) (ws + OFF_QRT8);
  i8*  qwx   = (i8*) (ws + OFF_QWX);
  int* qbx   = (int*)(ws + OFF_QBX);
  int* qbr   = (int*)(ws + OFF_QBR);
  int* lut   = (int*)(ws + OFF_LUT);
  u32* ring  = (u32*)(ws + OFF_RING);

  k0a_qx  <<<2048, 256, 0, stream>>>(x, (u32*)qx8, 32768*512/4);
  k0b_qwr <<<6144, 256, 0, stream>>>(W, R, qwT8, qrT8);
  k0c_misc<<<16,   256, 0, stream>>>(bx, br, qbx, qbr, lut, ring);
  k1_gemm_wx<<<3072, 256, 0, stream>>>(qx8, qwT8, qwx);
  k2_gru  <<<64, 256, 0, stream>>>(h0, qwx, qrT8, qbx, qbr, lut, ring, out);
}

// Round 9
// 1347.895 us; speedup vs baseline: 3.5743x; 1.1870x over previous
//
#include <hip/hip_runtime.h>

typedef unsigned short u16;
typedef unsigned int   u32;
typedef signed char    i8;
typedef __attribute__((ext_vector_type(8))) short  short8;
typedef __attribute__((ext_vector_type(8))) __bf16 bf16x8;
typedef __attribute__((ext_vector_type(4))) float  f32x4;

// ---------------- problem constants ----------------
#define NSTEP 512
#define NBG 4
#define NCG 16

// ---------------- workspace layout (bytes) ----------------
#define OFF_QXBF  0ull
#define SZ_QXBF   (32768ull*512*2)          // x quantized, bf16(int)
#define OFF_QWT   (OFF_QXBF + SZ_QXBF)
#define SZ_QWT    (1536ull*512*2)           // W^T quantized, bf16(int)
#define OFF_QRT   (OFF_QWT + SZ_QWT)        // R^T quantized, bf16(int)
#define OFF_QWX   (OFF_QRT + SZ_QWT)
#define SZ_QWX    (32768ull*1536)           // Wx quantized, int8
#define OFF_QBX   (OFF_QWX + SZ_QWX)        // 1536 int
#define OFF_QBR   (OFF_QBX + 6144)          // 1536 int
#define OFF_LUT   (OFF_QBR + 6144)          // 256 int sigmoid + 256 int tanh
#define OFF_RING  (OFF_LUT + 2048)          // 2 slots x 4 bg x 4096 u32 tagged h-words
#define RING_WORDS (2*4*4096)
#define SZ_RING   (RING_WORDS*4ull)
#define WS_NEED   (OFF_RING + SZ_RING)

// ---------------- helpers ----------------
__device__ __forceinline__ int iclip8(int v){ return v < -128 ? -128 : (v > 127 ? 127 : v); }

// round-half-even of (v / 2^k) for integer v (matches rintf/jnp.round on exact values)
__device__ __forceinline__ int rhe(int v, int k){
  int b = v >> k;                 // floor
  int r = v & ((1 << k) - 1);
  int half = 1 << (k - 1);
  return b + ((r > half) || (r == half && (b & 1)));
}

__device__ __forceinline__ u16 f2bf(float f){ return (u16)(__builtin_bit_cast(u32, f) >> 16); }

// quantize x*s to [-128,127], return exact bf16 of the (integer) result
__device__ __forceinline__ u16 qbf(float x, float s){
  float q = rintf(x * s);
  q = fminf(fmaxf(q, -128.f), 127.f);
  return f2bf(q);   // integers |q|<=128 are exact in bf16
}

__device__ __forceinline__ short bf_of_i8(u32 x){
  int v = (int)(signed char)(x & 0xFF);
  return (short)f2bf((float)v);
}

// MFMA wrapper: tolerate either short8- or bf16x8-typed builtin signature.
template<typename V>
__device__ __forceinline__ auto mfma_sel(V a, V b, f32x4 c, int)
  -> decltype(__builtin_amdgcn_mfma_f32_16x16x32_bf16(a, b, c, 0, 0, 0)) {
  return __builtin_amdgcn_mfma_f32_16x16x32_bf16(a, b, c, 0, 0, 0);
}
template<typename V>
__device__ __forceinline__ f32x4 mfma_sel(V a, V b, f32x4 c, long) {
  return __builtin_amdgcn_mfma_f32_16x16x32_bf16(
      __builtin_bit_cast(bf16x8, a), __builtin_bit_cast(bf16x8, b), c, 0, 0, 0);
}
__device__ __forceinline__ f32x4 mfma_bf16(short8 a, short8 b, f32x4 c){
  return mfma_sel(a, b, c, 0);
}

// tagged h-image: word index for (k, row), word = h(k)|h(k+1)<<8|tag<<16 (k even).
// w=k>>7 (consumer wave), t4=(k>>5)&3, g=(k>>3)&3, pair=(k&7)>>1
// consumer lane (g*16+row) of wave w loads one dwordx4 per t4 (4 tagged words).
__device__ __forceinline__ int img_widx(int k, int row){
  int w = k >> 7;
  int t4 = (k >> 5) & 3;
  int g  = (k >> 3) & 3;
  int pr = (k & 7) >> 1;
  return ((w*64 + g*16 + row)*4 + t4)*4 + pr;
}

// coherent (LLC, bypass L1/L2) store of one tagged word — no fence needed
__device__ __forceinline__ void llc_store(u32* p, u32 word){
  unsigned long long a = (unsigned long long)p;
  asm volatile("global_store_dword %0, %1, off sc0 sc1" :: "v"(a), "v"(word) : "memory");
}

// ---------------- phase 0: quantization / tables ----------------
__global__ void k0a_qx(const float* __restrict__ x, u16* __restrict__ qx, int n4){
  int i = blockIdx.x * blockDim.x + threadIdx.x;
  int st = gridDim.x * blockDim.x;
  for (; i < n4; i += st) {
    float4 v = ((const float4*)x)[i];
    ushort4 o;
    o.x = qbf(v.x, 16.f); o.y = qbf(v.y, 16.f);
    o.z = qbf(v.z, 16.f); o.w = qbf(v.w, 16.f);
    ((ushort4*)qx)[i] = o;
  }
}

__global__ void k0b_qwr(const float* __restrict__ W, const float* __restrict__ Rm,
                        u16* __restrict__ qwT, u16* __restrict__ qrT){
  int idx = blockIdx.x * 256 + threadIdx.x;       // 0 .. 2*786432-1
  if (idx >= 2*786432) return;
  int m = idx >= 786432;
  int rem = idx - m * 786432;                     // = k*1536 + n (coalesced read)
  int k = rem / 1536;
  int n = rem - k * 1536;
  const float* s = m ? Rm : W;
  u16* d = m ? qrT : qwT;
  d[n*512 + k] = qbf(s[rem], 1024.f);
}

__global__ void k0c_misc(const float* __restrict__ bx, const float* __restrict__ br,
                         int* __restrict__ qbx, int* __restrict__ qbr,
                         int* __restrict__ lut, u32* __restrict__ ring){
  int i = blockIdx.x * 256 + threadIdx.x;         // 4096 threads
  if (i < 1536) {
    int qx_ = (int)rintf(bx[i] * 256.f);
    int qr_ = (int)rintf(br[i] * 256.f);
    qbx[i] = iclip8(qx_);
    qbr[i] = iclip8(qr_);
  }
  if (i < 256) {
    double v = (i - 128) * 0.125;               // all possible pre-activations
    float sg = (float)(1.0 / (1.0 + exp(-v)));
    int qs = (int)rintf(sg * 256.f);
    lut[i] = qs < 0 ? 0 : (qs > 255 ? 255 : qs);
    float th = (float)tanh(v);
    lut[256 + i] = iclip8((int)rintf(th * 128.f));
  }
  // zero the ring EVERY launch: tags are >=1, so no garbage/leftover can match
#pragma unroll
  for (int r = 0; r < RING_WORDS/4096; r++)
    ring[r*4096 + i] = 0u;
}

// ---------------- phase 1: Wx = fq(xq @ Wq, 4), stored int8 ----------------
// 128x128 tile, BK=64, 4 waves each a 64x64 quadrant of 4x4 16x16 tiles.
__global__ __launch_bounds__(256) void k1_gemm_wx(const u16* __restrict__ qx,
                                                  const u16* __restrict__ qwT,
                                                  i8* __restrict__ qwx){
  __shared__ u16 xs[128][72];
  __shared__ u16 ws[128][72];
  int bid = blockIdx.x;
  int n0 = (bid % 12) * 128;
  int m0 = (bid / 12) * 128;
  int tid = threadIdx.x;
  int lane = tid & 63, wid = tid >> 6;
  int wm = wid >> 1, wn = wid & 1;
  int g = lane >> 4, l15 = lane & 15;

  f32x4 acc[4][4] = {};
  for (int kc = 0; kc < 512; kc += 64) {
    __syncthreads();
#pragma unroll
    for (int p = 0; p < 4; p++) {
      int idx = p*256 + tid;           // 1024 dwordx4 slots per matrix
      int r = idx >> 3, c8 = idx & 7;
      *(uint4*)&xs[r][c8*8] = *(const uint4*)&qx [(size_t)(m0 + r)*512 + kc + c8*8];
      *(uint4*)&ws[r][c8*8] = *(const uint4*)&qwT[(size_t)(n0 + r)*512 + kc + c8*8];
    }
    __syncthreads();
#pragma unroll
    for (int kt = 0; kt < 2; kt++) {
      short8 a[4], b[4];
#pragma unroll
      for (int t = 0; t < 4; t++) {
        a[t] = *(const short8*)&xs[wm*64 + t*16 + l15][kt*32 + g*8];
        b[t] = *(const short8*)&ws[wn*64 + t*16 + l15][kt*32 + g*8];
      }
#pragma unroll
      for (int i = 0; i < 4; i++)
#pragma unroll
        for (int j = 0; j < 4; j++)
          acc[i][j] = mfma_bf16(a[i], b[j], acc[i][j]);
    }
  }
  // epilogue: fq(acc, 4) relative to scale 1/(16*1024): q = rhe(acc/1024)
#pragma unroll
  for (int i = 0; i < 4; i++)
#pragma unroll
    for (int j = 0; j < 4; j++)
#pragma unroll
      for (int r = 0; r < 4; r++) {
        float s = acc[i][j][r];
        float q = fminf(fmaxf(rintf(s * 0x1p-10f), -128.f), 127.f);
        int row = m0 + wm*64 + i*16 + g*4 + r;   // C/D: row = 4*(lane>>4)+reg
        int col = n0 + wn*64 + j*16 + l15;       //      col = lane&15
        qwx[(size_t)row * 1536 + col] = (i8)(int)q;
      }
}

// ---------------- phase 2: 512-step recurrence ----------------
// 64 WGs: bg owns 16 batch rows, cg owns 32 h-cols (96 Rh cols). R-slice lives
// in registers as B-fragments for all 512 steps. h exchanged via LLC-coherent
// tagged words: no fences, no atomics, no flags — consumers poll data tags.
__global__ __launch_bounds__(256, 1) void k2_gru(const float* __restrict__ h0,
                                              const i8*  __restrict__ qwx,
                                              const u16* __restrict__ qrT,
                                              const int* __restrict__ qbx,
                                              const int* __restrict__ qbr,
                                              const int* __restrict__ lut,
                                              u32* __restrict__ ring,
                                              float* __restrict__ out){
  const int bid = blockIdx.x;
  const int bg  = (bid & 7) >> 1;                 // spread bg across XCDs
  const int cg  = ((bid >> 3) << 1) | (bid & 1);
  const int tid = threadIdx.x;
  const int lane = tid & 63, wid = tid >> 6;      // wave = K-slice of 128
  const int g = lane >> 4, l15 = lane & 15;

  __shared__ float red[4][16][97];                // padded: kill bank conflicts
  __shared__ int   rhb[16][96];                   // quantized Rh+br
  __shared__ int   l_bx[96], l_br[96];
  __shared__ int   l_sig[256], l_th[256];

  if (tid < 256) { l_sig[tid] = lut[tid]; l_th[tid] = lut[256 + tid]; }
  if (tid < 96) {
    int gate = tid / 32, c = tid - gate*32;
    int colg = gate*512 + cg*32 + c;
    l_bx[tid] = qbx[colg];
    l_br[tid] = qbr[colg];
  }

  // ---- R fragments (B operand), resident in registers: 6 n-tiles x 4 k-tiles
  short8 rf[6][4];
#pragma unroll
  for (int n = 0; n < 6; n++) {
    int colg = (n >> 1)*512 + cg*32 + ((n & 1) << 4) + l15;   // B: col = lane&15
#pragma unroll
    for (int t4 = 0; t4 < 4; t4++)
      rf[n][t4] = *(const short8*)&qrT[(size_t)colg*512 + wid*128 + t4*32 + g*8];
  }

  // ---- own h state: 2 elements per thread (row = tid>>4, cols c0,c0+1)
  const int row = tid >> 4;
  const int c0  = (tid & 15) << 1;
  int qh0 = iclip8((int)rintf(h0[(size_t)(bg*16 + row)*512 + cg*32 + c0    ] * 128.f));
  int qh1 = iclip8((int)rintf(h0[(size_t)(bg*16 + row)*512 + cg*32 + c0 + 1] * 128.f));

  // publish h(0): slot 0, tag 1  (tag of h(T) = T+1, never 0)
  {
    u32* dst = ring + (size_t)(0*4 + bg) * 4096;
    u32 word = (u32)(qh0 & 0xFF) | ((u32)(qh1 & 0xFF) << 8) | (1u << 16);
    llc_store(&dst[img_widx(cg*32 + c0, row)], word);
  }
  __syncthreads();

  const unsigned long long pollbase0 =
      (unsigned long long)ring + (unsigned long long)((wid*64 + lane)*4) * 16ull;

  for (int t = 0; t < NSTEP; t++) {
    // prefetch Wx for this step (plain cached loads; independent of h)
    const i8* wxp = qwx + (size_t)t*(64*1536) + (size_t)(bg*16 + row)*1536 + cg*32;
    int wz0 = wxp[c0],        wz1 = wxp[c0 + 1];
    int wr0 = wxp[512 + c0],  wr1 = wxp[512 + c0 + 1];
    int wg0 = wxp[1024 + c0], wg1 = wxp[1024 + c0 + 1];

    // ---- poll the 16 tagged words this lane needs (h(t), slot t&1, tag t+1)
    const u32 want = (u32)(t + 1);
    unsigned long long pb = pollbase0 + (unsigned long long)(((t & 1)*4 + bg)*4096) * 4ull;
    uint4 v0, v1, v2, v3;
    bool ok;
    do {
      asm volatile(
        "global_load_dwordx4 %0, %4, off sc0 sc1\n\t"
        "global_load_dwordx4 %1, %4, off offset:16 sc0 sc1\n\t"
        "global_load_dwordx4 %2, %4, off offset:32 sc0 sc1\n\t"
        "global_load_dwordx4 %3, %4, off offset:48 sc0 sc1\n\t"
        "s_waitcnt vmcnt(0)"
        : "=&v"(v0), "=&v"(v1), "=&v"(v2), "=&v"(v3)
        : "v"(pb)
        : "memory");
      u32 m;
      m  = (v0.x >> 16) ^ want; m |= (v0.y >> 16) ^ want;
      m |= (v0.z >> 16) ^ want; m |= (v0.w >> 16) ^ want;
      m |= (v1.x >> 16) ^ want; m |= (v1.y >> 16) ^ want;
      m |= (v1.z >> 16) ^ want; m |= (v1.w >> 16) ^ want;
      m |= (v2.x >> 16) ^ want; m |= (v2.y >> 16) ^ want;
      m |= (v2.z >> 16) ^ want; m |= (v2.w >> 16) ^ want;
      m |= (v3.x >> 16) ^ want; m |= (v3.y >> 16) ^ want;
      m |= (v3.z >> 16) ^ want; m |= (v3.w >> 16) ^ want;
      ok = (m == 0);
      if (!ok) __builtin_amdgcn_s_sleep(1);
    } while (!ok);

    // ---- unpack tagged int8 pairs -> bf16 A fragments
    short8 af[4];
    {
      uint4 wv[4] = {v0, v1, v2, v3};
#pragma unroll
      for (int t4 = 0; t4 < 4; t4++) {
        uint4 w = wv[t4];
        short8 f;
        f[0] = bf_of_i8(w.x); f[1] = bf_of_i8(w.x >> 8);
        f[2] = bf_of_i8(w.y); f[3] = bf_of_i8(w.y >> 8);
        f[4] = bf_of_i8(w.z); f[5] = bf_of_i8(w.z >> 8);
        f[6] = bf_of_i8(w.w); f[7] = bf_of_i8(w.w >> 8);
        af[t4] = f;
      }
    }

    f32x4 acc[6] = {};
#pragma unroll
    for (int t4 = 0; t4 < 4; t4++)
#pragma unroll
      for (int n = 0; n < 6; n++)
        acc[n] = mfma_bf16(af[t4], rf[n][t4], acc[n]);

#pragma unroll
    for (int n = 0; n < 6; n++)
#pragma unroll
      for (int r = 0; r < 4; r++)
        red[wid][g*4 + r][n*16 + l15] = acc[n][r];
    __syncthreads();

    // reduce K-slices, then Rh -> Rh+br quantization (all exact integers)
#pragma unroll
    for (int ii = 0; ii < 6; ii++) {
      int lin = tid*6 + ii;                 // 0..1535 over [16][96]
      int rr2 = lin / 96, cc = lin - rr2*96;
      float S = red[0][rr2][cc] + red[1][rr2][cc] + red[2][rr2][cc] + red[3][rr2][cc];
      int qRh = iclip8((int)rintf(S * 0x1p-13f));       // fq(h@R, 4)
      rhb[rr2][cc] = iclip8(rhe(qRh*16 + l_br[cc], 4)); // fq(Rh+br, 4)
    }
    __syncthreads();

    // gates + state update for this thread's 2 elements
    u32* dst = ring + (size_t)(((t + 1) & 1)*4 + bg) * 4096;
    float* op = out + ((size_t)t*64 + bg*16 + row)*512 + cg*32;

    {
      int rz = rhb[row][c0], rr = rhb[row][32 + c0], rg = rhb[row][64 + c0];
      int uz = l_sig[128 + iclip8(rhe(16*(wz0 + rz) + l_bx[c0],      5))];
      int ur = l_sig[128 + iclip8(rhe(16*(wr0 + rr) + l_bx[32 + c0], 5))];
      int qrh = iclip8(rhe(ur * rg, 8));
      int qg  = l_th[128 + iclip8(rhe(16*(wg0 + qrh) + l_bx[64 + c0], 5))];
      int qold = iclip8(rhe(uz * qh0, 8));
      int qnew = iclip8(rhe((256 - uz) * qg, 8));
      qh0 = iclip8(qold + qnew);
    }
    {
      int c1 = c0 + 1;
      int rz = rhb[row][c1], rr = rhb[row][32 + c1], rg = rhb[row][64 + c1];
      int uz = l_sig[128 + iclip8(rhe(16*(wz1 + rz) + l_bx[c1],      5))];
      int ur = l_sig[128 + iclip8(rhe(16*(wr1 + rr) + l_bx[32 + c1], 5))];
      int qrh = iclip8(rhe(ur * rg, 8));
      int qg  = l_th[128 + iclip8(rhe(16*(wg1 + qrh) + l_bx[64 + c1], 5))];
      int qold = iclip8(rhe(uz * qh1, 8));
      int qnew = iclip8(rhe((256 - uz) * qg, 8));
      qh1 = iclip8(qold + qnew);
    }
    // publish h(t+1) FIRST (earliest cross-WG visibility), then out
    {
      u32 word = (u32)(qh0 & 0xFF) | ((u32)(qh1 & 0xFF) << 8) | ((u32)(t + 2) << 16);
      llc_store(&dst[img_widx(cg*32 + c0, row)], word);
    }
    op[c0]     = qh0 * 0.0078125f;
    op[c0 + 1] = qh1 * 0.0078125f;
    __syncthreads();   // protect red[]/rhb[] reuse next step
  }
}

// ---------------- launch ----------------
extern "C" void kernel_launch(void* const* d_in, const int* in_sizes, int n_in,
                              void* d_out, int out_size, void* d_ws, size_t ws_size,
                              hipStream_t stream) {
  const float* x  = (const float*)d_in[0];
  const float* h0 = (const float*)d_in[1];
  const float* W  = (const float*)d_in[2];
  const float* R  = (const float*)d_in[3];
  const float* bx = (const float*)d_in[4];
  const float* br = (const float*)d_in[5];
  float* out = (float*)d_out;

  if (ws_size < WS_NEED) return;   // insufficient scratch; fail loudly

  char* ws = (char*)d_ws;
  u16* qxbf  = (u16*)(ws + OFF_QXBF);
  u16* qwT   = (u16*)(ws + OFF_QWT);
  u16* qrT   = (u16*)(ws + OFF_QRT);
  i8*  qwx   = (i8*) (ws + OFF_QWX);
  int* qbx   = (int*)(ws + OFF_QBX);
  int* qbr   = (int*)(ws + OFF_QBR);
  int* lut   = (int*)(ws + OFF_LUT);
  u32* ring  = (u32*)(ws + OFF_RING);

  k0a_qx  <<<2048, 256, 0, stream>>>(x, qxbf, 32768*512/4);
  k0b_qwr <<<6144, 256, 0, stream>>>(W, R, qwT, qrT);
  k0c_misc<<<16,   256, 0, stream>>>(bx, br, qbx, qbr, lut, ring);
  k1_gemm_wx<<<3072, 256, 0, stream>>>(qxbf, qwT, qwx);
  k2_gru  <<<64, 256, 0, stream>>>(h0, qwx, qrT, qbx, qbr, lut, ring, out);
}